// Round 2
// baseline (95.301 us; speedup 1.0000x reference)
//
#include <hip/hip_runtime.h>
#include <math.h>

#define NUM_GRAPHS 16
#define PI_F 3.14159265358979323846f
#define INV_SQRT_2PI 0.3989422804014327f

// Kernel A (1 block, 256 thr):
//  - parallel boundary scan of sorted `batch` -> node_start[17]
//  - self-energy per graph via wave-per-graph shuffle reduction (no atomics)
//  - out[g] = -0.5 * sum(q^2) / sqrt(2*pi)
__global__ void __launch_bounds__(256)
gto_init_kernel(const float* __restrict__ q,
                const int* __restrict__ batch, int n_nodes,
                float* __restrict__ out,
                int* __restrict__ node_start /* NUM_GRAPHS+1 ints in ws */) {
    __shared__ int ns[NUM_GRAPHS + 1];
    int t = threadIdx.x;

    if (t == 0) {
        ns[0] = 0;
        int bl = batch[n_nodes - 1];
        for (int g = bl + 1; g <= NUM_GRAPHS; ++g) ns[g] = n_nodes;
    }
    __syncthreads();  // ns tail init visible before boundary writes merge

    // boundary scan: batch sorted; where batch[i] != batch[i+1], segments start
    for (int i = t; i < n_nodes - 1; i += 256) {
        int b0 = batch[i];
        int b1 = batch[i + 1];
        if (b0 != b1) {
            for (int g = b0 + 1; g <= b1; ++g) ns[g] = i + 1;
        }
    }
    __syncthreads();

    int wave = t >> 6;
    int lane = t & 63;
    // wave w handles graphs w, w+4, w+8, w+12
    for (int g = wave; g < NUM_GRAPHS; g += 4) {
        int s = ns[g], e = ns[g + 1];
        float acc = 0.f;
        for (int j = s + lane; j < e; j += 64) {
            float qj = q[j];
            acc = fmaf(qj, qj, acc);
        }
        #pragma unroll
        for (int off = 32; off > 0; off >>= 1) acc += __shfl_xor(acc, off, 64);
        if (lane == 0) out[g] = -0.5f * acc * INV_SQRT_2PI;
    }

    if (t <= NUM_GRAPHS) node_start[t] = ns[t];
}

// Kernel B: 16 k's per wave, 4 lanes per k.
// lane = noff*16 + ksub ; ksub = lane & 15 selects k, noff = lane >> 4 strides nodes.
#define K_PER_WAVE 16
#define WAVES_PER_BLOCK 4
#define K_PER_BLOCK (K_PER_WAVE * WAVES_PER_BLOCK)

__global__ void __launch_bounds__(256)
gto_energy_kernel(const float* __restrict__ kvec,   // [K,3]
                  const float* __restrict__ knorm2, // [K]
                  const int*   __restrict__ kbatch, // [K] sorted
                  const float* __restrict__ k0mask, // [K]
                  const float* __restrict__ q,      // [N]
                  const float* __restrict__ pos,    // [N,3]
                  const float* __restrict__ volume, // [B]
                  const int*   __restrict__ node_start, // [B+1]
                  float* __restrict__ out, int K) {
    __shared__ float gacc[NUM_GRAPHS];
    int t = threadIdx.x;
    if (t < NUM_GRAPHS) gacc[t] = 0.f;
    __syncthreads();

    int wave = t >> 6;
    int lane = t & 63;
    int ksub = lane & 15;
    int noff = lane >> 4;

    int k = (blockIdx.x * WAVES_PER_BLOCK + wave) * K_PER_WAVE + ksub;
    if (k < K) {
        int g = kbatch[k];
        float kx = kvec[3 * k + 0];
        float ky = kvec[3 * k + 1];
        float kz = kvec[3 * k + 2];
        int s = node_start[g];
        int e = node_start[g + 1];

        float C = 0.f, S = 0.f;
        for (int j = s + noff; j < e; j += 4) {
            float px = pos[3 * j + 0];
            float py = pos[3 * j + 1];
            float pz = pos[3 * j + 2];
            float inner = fmaf(kx, px, fmaf(ky, py, kz * pz));
            float sv, cv;
            __sincosf(inner, &sv, &cv);
            float qj = q[j];
            C = fmaf(cv, qj, C);
            S = fmaf(sv, qj, S);
        }
        // reduce the 4 node-offset partials: lanes {l, l^16, l^32, l^48}
        C += __shfl_xor(C, 16, 64);
        S += __shfl_xor(S, 16, 64);
        C += __shfl_xor(C, 32, 64);
        S += __shfl_xor(S, 32, 64);

        if (noff == 0) {
            float kn2 = knorm2[k];
            float fs = __expf(-0.5f * kn2);  // sigma = 1
            float kfac = (k0mask[k] > 0.f) ? 0.f : 1.f / kn2;
            float e_k = 4.f * PI_F * kfac * fs * fs * (C * C + S * S) / volume[g];
            atomicAdd(&gacc[g], e_k);
        }
    }
    __syncthreads();
    if (t < NUM_GRAPHS && gacc[t] != 0.f) {
        atomicAdd(&out[t], gacc[t]);
    }
}

extern "C" void kernel_launch(void* const* d_in, const int* in_sizes, int n_in,
                              void* d_out, int out_size, void* d_ws, size_t ws_size,
                              hipStream_t stream) {
    const float* k_vectors  = (const float*)d_in[0];  // [K,3]
    const float* k_norm2    = (const float*)d_in[1];  // [K]
    const int*   k_batch    = (const int*)  d_in[2];  // [K]
    const float* k0_mask    = (const float*)d_in[3];  // [K]
    const float* src_feats  = (const float*)d_in[4];  // [N,1]
    const float* positions  = (const float*)d_in[5];  // [N,3]
    const int*   batch      = (const int*)  d_in[6];  // [N]
    const float* volume     = (const float*)d_in[7];  // [B]
    // d_in[8] = pbc (bool [B,3]) — unused by the math

    int K = in_sizes[1];
    int N = in_sizes[4];
    float* out = (float*)d_out;
    int* node_start = (int*)d_ws;  // NUM_GRAPHS+1 ints

    gto_init_kernel<<<1, 256, 0, stream>>>(src_feats, batch, N, out, node_start);

    int blocks = (K + K_PER_BLOCK - 1) / K_PER_BLOCK;
    gto_energy_kernel<<<blocks, 256, 0, stream>>>(
        k_vectors, k_norm2, k_batch, k0_mask, src_feats, positions,
        volume, node_start, out, K);
}